// Round 7
// baseline (628.603 us; speedup 1.0000x reference)
//
#include <hip/hip_runtime.h>
#include <math.h>

#define B_ 32
#define D_ 16
#define T_ 1024
#define P_ 64
#define L_ 32
#define XSTR 20            // xT row: 16 x + x2 + pad (80 B)
#define BIGV 1e30f
#define CROW 66            // c-tile row stride (words): reads at 65*li -> bank=li (conflict-free)
#define CGRP (32*CROW)     // 2112 words per group
#define CBUF (2*CGRP)      // 4224 words per buffer (2 groups)
#define PROW 20            // pattern row stride in LDS (16B aligned)

typedef float v2f __attribute__((ext_vector_type(2)));

// ---- DPP helper ------------------------------------------------------------
template<int CTRL, int ROW_MASK, bool BC>
__device__ __forceinline__ float dpp_mov(float old_, float src) {
  int o = __builtin_bit_cast(int, old_);
  int s = __builtin_bit_cast(int, src);
  int r = __builtin_amdgcn_update_dpp(o, s, CTRL, ROW_MASK, 0xf, BC);
  return __builtin_bit_cast(float, r);
}
// wave_shr:1 — lane n gets lane n-1 (lane 0 keeps own value; fixed by cndmask)
__device__ __forceinline__ float shr1(float v) {
  return dpp_mov<0x138, 0xf, false>(v, v);
}

// ---- transpose: x[b][d][t] -> xT[b][t][XSTR] (x[0..15], x2 at [16]) --------
__global__ void dtw_transpose(const float* __restrict__ x,
                              float* __restrict__ xT) {
  int gid = blockIdx.x * blockDim.x + threadIdx.x;
  if (gid >= B_ * T_) return;
  int b = gid >> 10;
  int j = gid & (T_ - 1);
  float v[D_];
  float s = 0.f;
#pragma unroll
  for (int d = 0; d < D_; ++d) {
    v[d] = x[((size_t)(b * D_ + d)) * T_ + j];
    s = fmaf(v[d], v[d], s);
  }
  float* row = xT + (size_t)gid * XSTR;
  float4* dst = (float4*)row;
#pragma unroll
  for (int q = 0; q < 4; ++q)
    dst[q] = make_float4(v[4*q], v[4*q+1], v[4*q+2], v[4*q+3]);
  row[16] = s;
}

struct XCol { float4 a0, a1, a2, a3; float s; };

// ---- main kernel: anti-diagonal DTW ---------------------------------------
// Grid = B*P/2 = 1024 blocks x 64 threads (1 wave). Lanes: li = pattern pos i,
// grp = which of 2 patterns. Step k computes cells (i, j=k-i); deps all come
// from steps k-1/k-2 => only 2 DPP per step (no 10-op scans — R1..R6's floor).
// Costs per 32-col tile precomputed into LDS by a dense pk_fma phase.
__global__ __launch_bounds__(64, 1) void dtw_kernel(
    const float* __restrict__ xT,     // [B][T][XSTR]
    const float* __restrict__ patts,  // [P][D][L]
    const float* __restrict__ wp,
    float* __restrict__ out)          // [B][P][T]
{
  __shared__ float lds_raw[1 + 2*CBUF + 2*32*PROW];  // guard + c-tiles + patt
  float* Lc = lds_raw + 1;
  float* Lp = Lc + 2*CBUF;

  const int tid = threadIdx.x;
  const int li  = tid & 31;
  const int grp = tid >> 5;
  const int b   = blockIdx.x >> 5;                 // 32 pattern-pairs per b
  const int p   = ((blockIdx.x & 31) << 1) | grp;
  const float w = wp[0];
  const bool l0 = (li == 0), l1 = (li == 1), l31 = (li == 31);

  // ---- pattern row (16 vals + p2) -> LDS [grp][i][PROW] ----
  {
    float pd[16]; float p2 = 0.f;
#pragma unroll
    for (int d = 0; d < 16; ++d) {
      float t = patts[((size_t)(p * 16 + d) << 5) + li];
      pd[d] = t; p2 = fmaf(t, t, p2);
    }
    float* pr = Lp + (grp * 32 + li) * PROW;
    *(float4*)(pr + 0)  = make_float4(pd[0],  pd[1],  pd[2],  pd[3]);
    *(float4*)(pr + 4)  = make_float4(pd[4],  pd[5],  pd[6],  pd[7]);
    *(float4*)(pr + 8)  = make_float4(pd[8],  pd[9],  pd[10], pd[11]);
    *(float4*)(pr + 12) = make_float4(pd[12], pd[13], pd[14], pd[15]);
    pr[16] = p2;
  }
  // ---- BIG-init buf0 history slots [0,30] (pre-j=0 diagonal reads) ----
  {
    float* h = Lc + grp * CGRP + li * CROW;
#pragma unroll
    for (int q = 0; q < 31; ++q) h[q] = BIGV;
  }

  const float* xg = xT + (size_t)b * T_ * XSTR;
  float* orow = out + (size_t)(b * P_ + p) * T_;

  const float* rd = Lc + grp * CGRP + li * 65;   // DP read: +31+s => row li, slot s-li+31
  float* wmain = Lc + grp * CGRP + 31 + li;      // fill main: + i*CROW (+buf)
  float* wdup  = Lc + grp * CGRP - 1 + li;       // fill dup (lane li=0 hits pad/guard)
  const float* prA = Lp + grp * 32 * PROW;

  XCol xa, xb;
  auto loadx = [&](int t, XCol& X) {
    const float* cp = xg + (size_t)(t * 32 + li) * XSTR;
    X.a0 = *(const float4*)cp;        X.a1 = *(const float4*)(cp + 4);
    X.a2 = *(const float4*)(cp + 8);  X.a3 = *(const float4*)(cp + 12);
    X.s  = cp[16];
  };

  // fill tile: lane = column jj=li; loop i over pattern rows (LDS broadcast)
  auto fill = [&](int BO, const XCol& X) {
    float* wm = wmain + BO;
    float* wd = wdup + (BO ^ CBUF);
#pragma unroll
    for (int i = 0; i < 32; ++i) {
      const float* pr = prA + i * PROW;
      float4 q0 = *(const float4*)pr;
      float4 q1 = *(const float4*)(pr + 4);
      float4 q2 = *(const float4*)(pr + 8);
      float4 q3 = *(const float4*)(pr + 12);
      float pp2 = pr[16];
      v2f a0 = {0.f, 0.f}, a1 = {0.f, 0.f};
      a0 = __builtin_elementwise_fma(*(const v2f*)&X.a0.x, *(const v2f*)&q0.x, a0);
      a1 = __builtin_elementwise_fma(*(const v2f*)&X.a0.z, *(const v2f*)&q0.z, a1);
      a0 = __builtin_elementwise_fma(*(const v2f*)&X.a1.x, *(const v2f*)&q1.x, a0);
      a1 = __builtin_elementwise_fma(*(const v2f*)&X.a1.z, *(const v2f*)&q1.z, a1);
      a0 = __builtin_elementwise_fma(*(const v2f*)&X.a2.x, *(const v2f*)&q2.x, a0);
      a1 = __builtin_elementwise_fma(*(const v2f*)&X.a2.z, *(const v2f*)&q2.z, a1);
      a0 = __builtin_elementwise_fma(*(const v2f*)&X.a3.x, *(const v2f*)&q3.x, a0);
      a1 = __builtin_elementwise_fma(*(const v2f*)&X.a3.z, *(const v2f*)&q3.z, a1);
      v2f as = a0 + a1;
      float dot = as.x + as.y;
      float c = fmaf(-2.f, dot, X.s + pp2);
      wm[i * CROW] = c;        // main: buf, slot 31+jj
      wd[i * CROW] = c;        // dup into other buf, slot jj-1 (jj=0 -> pad)
    }
  };

  // DP state: Da = D[i, k-i], Db = D[i-1, k-i+1], Dbp = Db(k-2), sb2 = shifted Db(k-2)
  float Da = BIGV, Dbp = BIGV, sb2 = BIGV;
  float Db = l0 ? 0.f : BIGV;    // seed D[-1,0]=0 for cell (0,0); scrubbed after step 1

  auto dpstep = [&](const float* rb, int soff, int j) -> float {
    float ca = rb[soff];                       // cost(i, k-i)
    float cb = shr1(ca);                       // cost(i-1, k-i+1)
    float sb1 = shr1(Db);                      // D[i-2, k-i+1] (from k-1)
    float tA = fminf(Db, w * fminf(Da, Dbp));
    float Dan = ca + tA;
    float tB = fminf(sb1, w * fminf(Db, sb2));
    float Dbn = cb + tB;
    Dbp = Db; sb2 = sb1;
    Db = l0 ? BIGV : Dbn;
    Da = Dan;
    if ((unsigned)j < (unsigned)T_ && l31) orow[j] = sqrtf(Da);
    return ca;
  };

  auto dptile = [&](int BO, int t, bool first) {
    const float* rb = rd + BO + 31;
    const int jb = t * 32 - 31;
#pragma unroll
    for (int s = 0; s < 32; ++s) {
      float ca0 = dpstep(rb, s, jb + s);
      if (first && s == 0) {
        Da  = l0 ? ca0 : Da;     // cell (0,0) = cost (seed path, exact)
        Dbp = l0 ? BIGV : Dbp;   // scrub seed out of D[i-1,j-1] path
        sb2 = l1 ? BIGV : sb2;   // scrub shifted seed out of lane1's path
      }
    }
  };

  // ---- pipeline: fill(t) consumes x(t), prefetch x(t+1), then DP(t) ----
  loadx(0, xa);
  fill(0, xa); loadx(1, xb); dptile(0, 0, true);
  for (int t2 = 0; t2 < 15; ++t2) {
    const int t = 2 * t2 + 1;
    fill(CBUF, xb); loadx(t + 1, xa); dptile(CBUF, t, false);
    fill(0, xa);    loadx(t + 2, xb); dptile(0, t + 1, false);
  }
  fill(CBUF, xb); dptile(CBUF, 31, false);
  dptile(0, 32, false);   // epilogue: j = 993..1023 via dup'd history
}

extern "C" void kernel_launch(void* const* d_in, const int* in_sizes, int n_in,
                              void* d_out, int out_size, void* d_ws, size_t ws_size,
                              hipStream_t stream) {
  const float* x     = (const float*)d_in[0];
  const float* patts = (const float*)d_in[1];
  const float* w     = (const float*)d_in[2];
  float* out = (float*)d_out;

  float* xT = (float*)d_ws;                  // B*T*XSTR floats = 2.62 MB

  dtw_transpose<<<(B_ * T_ + 255) / 256, 256, 0, stream>>>(x, xT);
  dtw_kernel<<<B_ * (P_ / 2), 64, 0, stream>>>(xT, patts, w, out);
}

// Round 8
// 376.663 us; speedup vs baseline: 1.6689x; 1.6689x over previous
//
#include <hip/hip_runtime.h>
#include <math.h>

#define B_ 32
#define D_ 16
#define T_ 1024
#define P_ 64
#define L_ 32
#define XSTR 20            // xT row: 16 x + x2 + pad (80 B)
#define TILE 128           // columns per LDS tile
#define KCH 512            // output cols per chunk (2 chunks)
#define WUP 384            // warm-up cols (3 tiles); w^384 = 2.4e-4

typedef float v2f __attribute__((ext_vector_type(2)));

// ---- DPP helpers -----------------------------------------------------------
template<int CTRL, int ROW_MASK, bool BC>
__device__ __forceinline__ float dpp_mov(float old_, float src) {
  int o = __builtin_bit_cast(int, old_);
  int s = __builtin_bit_cast(int, src);
  int r = __builtin_amdgcn_update_dpp(o, s, CTRL, ROW_MASK, 0xf, BC);
  return __builtin_bit_cast(float, r);
}

// Inclusive prefix-sum over each 32-lane half of the wave.
__device__ __forceinline__ float scan_sum32(float v) {
  v += dpp_mov<0x111, 0xf, true>(0.f, v);   // row_shr:1
  v += dpp_mov<0x112, 0xf, true>(0.f, v);   // row_shr:2
  v += dpp_mov<0x114, 0xf, true>(0.f, v);   // row_shr:4
  v += dpp_mov<0x118, 0xf, true>(0.f, v);   // row_shr:8
  v += dpp_mov<0x142, 0xa, false>(0.f, v);  // row_bcast15 -> rows 1,3
  return v;
}

// Inclusive prefix-min over each 32-lane half (old=v; min(v,v)=v identity).
__device__ __forceinline__ float scan_min32(float v) {
  v = fminf(v, dpp_mov<0x111, 0xf, false>(v, v));
  v = fminf(v, dpp_mov<0x112, 0xf, false>(v, v));
  v = fminf(v, dpp_mov<0x114, 0xf, false>(v, v));
  v = fminf(v, dpp_mov<0x118, 0xf, false>(v, v));
  v = fminf(v, dpp_mov<0x142, 0xa, false>(v, v));
  return v;
}

// ---- transpose: x[b][d][t] -> xT[b][t][XSTR] (x[0..15], x2 at [16]) --------
__global__ void dtw_transpose(const float* __restrict__ x,
                              float* __restrict__ xT) {
  int gid = blockIdx.x * blockDim.x + threadIdx.x;   // 0 .. B*T-1
  if (gid >= B_ * T_) return;
  int b = gid >> 10;
  int j = gid & (T_ - 1);
  float v[D_];
  float s = 0.f;
#pragma unroll
  for (int d = 0; d < D_; ++d) {
    v[d] = x[((size_t)(b * D_ + d)) * T_ + j];
    s = fmaf(v[d], v[d], s);
  }
  float* row = xT + (size_t)gid * XSTR;
  float4* dst = (float4*)row;
#pragma unroll
  for (int q = 0; q < 4; ++q)
    dst[q] = make_float4(v[4*q], v[4*q+1], v[4*q+2], v[4*q+3]);
  row[16] = s;
}

// ---- main DTW kernel -------------------------------------------------------
// Grid = B * (P/16) * 2 = 256 blocks x 256 threads. Each 32-lane group runs
// TWO patterns (same b) as interleaved independent DP streams: the second
// stream's issue fills the first stream's dependency stalls (R4 counters:
// 143 busy / 477 stall cyc per column at 1 wave/SIMD), and both streams share
// the x-column LDS reads + addressing. 2 time-chunks (warm-started with a
// cumsum column WUP cols early) shorten the serial path to 896 steps at
// 1.375x work; truncation error w^WUP ~ 2.4e-4 (absmax contribution ~1e-3).
__global__ __launch_bounds__(256, 1) void dtw_kernel(
    const float* __restrict__ xT,     // [B][T][XSTR]
    const float* __restrict__ patts,  // [P][D][L]
    const float* __restrict__ wp,
    float* __restrict__ out)          // [B][P][T]
{
  __shared__ float lds[2][TILE * XSTR];   // 2 x 10240 B

  const int tid = threadIdx.x;
  const int li  = tid & 31;
  const int grp = tid >> 5;
  const int ch  = blockIdx.x & 1;
  const int pg  = (blockIdx.x >> 1) & 3;
  const int b   = blockIdx.x >> 3;
  const int pA  = pg * 16 + (grp << 1);
  const int pB  = pA + 1;
  const float w = wp[0];
  const bool l0 = (li == 0), l31 = (li == 31);

  const int j0     = ch ? (KCH - WUP) : 0;   // 0 or 128
  const int jstore = ch * KCH;               // 0 or 512
  const int NT     = ch ? 7 : 4;             // tiles (128 cols each)

  // pattern fragments, packed for v_pk_fma_f32
  v2f pa[8], pb[8];
  float p2A = 0.f, p2B = 0.f;
#pragma unroll
  for (int d = 0; d < D_; ++d) {
    float ta = patts[((size_t)pA * D_ + d) * L_ + li];
    float tb = patts[((size_t)pB * D_ + d) * L_ + li];
    ((float*)pa)[d] = ta;  ((float*)pb)[d] = tb;
    p2A = fmaf(ta, ta, p2A);
    p2B = fmaf(tb, tb, p2B);
  }

  const float4* xg = (const float4*)(xT + ((size_t)b * T_ + j0) * XSTR);
  float* orowA = out + ((size_t)(b * P_ + pA)) * T_;
  float* orowB = out + ((size_t)(b * P_ + pB)) * T_;

  const int QT = TILE * XSTR / 4;   // 640 float4 per tile

  // ---- stage tile 0 ----
  float4 st0, st1, st2;
  st0 = xg[tid];
  st1 = xg[tid + 256];
  if (tid < QT - 512) st2 = xg[tid + 512];
  ((float4*)lds[0])[tid] = st0;
  ((float4*)lds[0])[tid + 256] = st1;
  if (tid < QT - 512) ((float4*)lds[0])[tid + 512] = st2;
  __syncthreads();

  float dcA = 0.f, dcB = 0.f;   // init col handled via (j==j0) select

  for (int t = 0; t < NT; ++t) {
    const int tn = (t + 1 < NT) ? t + 1 : t;
    const float4* src = xg + (size_t)tn * QT;
    st0 = src[tid];
    st1 = src[tid + 256];
    if (tid < QT - 512) st2 = src[tid + 512];

    const float* buf = lds[t & 1];
    const int jb = j0 + t * TILE;

#pragma unroll 4
    for (int k = 0; k < TILE; ++k) {
      const int j = jb + k;
      const float* cp = buf + k * XSTR;
      float4 r0 = *(const float4*)(cp);
      float4 r1 = *(const float4*)(cp + 4);
      float4 r2 = *(const float4*)(cp + 8);
      float4 r3 = *(const float4*)(cp + 12);
      float rs = cp[16];

      // two dots via packed FMA (streams A, B share the column regs)
      v2f qa0 = {0.f, 0.f}, qa1 = {0.f, 0.f};
      v2f qb0 = {0.f, 0.f}, qb1 = {0.f, 0.f};
      qa0 = __builtin_elementwise_fma(*(const v2f*)&r0.x, pa[0], qa0);
      qb0 = __builtin_elementwise_fma(*(const v2f*)&r0.x, pb[0], qb0);
      qa1 = __builtin_elementwise_fma(*(const v2f*)&r0.z, pa[1], qa1);
      qb1 = __builtin_elementwise_fma(*(const v2f*)&r0.z, pb[1], qb1);
      qa0 = __builtin_elementwise_fma(*(const v2f*)&r1.x, pa[2], qa0);
      qb0 = __builtin_elementwise_fma(*(const v2f*)&r1.x, pb[2], qb0);
      qa1 = __builtin_elementwise_fma(*(const v2f*)&r1.z, pa[3], qa1);
      qb1 = __builtin_elementwise_fma(*(const v2f*)&r1.z, pb[3], qb1);
      qa0 = __builtin_elementwise_fma(*(const v2f*)&r2.x, pa[4], qa0);
      qb0 = __builtin_elementwise_fma(*(const v2f*)&r2.x, pb[4], qb0);
      qa1 = __builtin_elementwise_fma(*(const v2f*)&r2.z, pa[5], qa1);
      qb1 = __builtin_elementwise_fma(*(const v2f*)&r2.z, pb[5], qb1);
      qa0 = __builtin_elementwise_fma(*(const v2f*)&r3.x, pa[6], qa0);
      qb0 = __builtin_elementwise_fma(*(const v2f*)&r3.x, pb[6], qb0);
      qa1 = __builtin_elementwise_fma(*(const v2f*)&r3.z, pa[7], qa1);
      qb1 = __builtin_elementwise_fma(*(const v2f*)&r3.z, pb[7], qb1);
      v2f qa = qa0 + qa1, qb = qb0 + qb1;
      float cA = fmaf(-2.f, qa.x + qa.y, rs + p2A);
      float cB = fmaf(-2.f, qb.x + qb.y, rs + p2B);

      // stream A
      float SA = scan_sum32(cA);
      float puA = dpp_mov<0x138, 0xf, false>(dcA, dcA);  // wave_shr:1
      puA = l0 ? dcA : puA;
      float eA = fmaf(w, fminf(dcA, puA), cA - SA);
      float MA = scan_min32(eA);
      dcA = SA + ((j == j0) ? 0.f : MA);

      // stream B (independent chain — fills A's stall cycles)
      float SB = scan_sum32(cB);
      float puB = dpp_mov<0x138, 0xf, false>(dcB, dcB);
      puB = l0 ? dcB : puB;
      float eB = fmaf(w, fminf(dcB, puB), cB - SB);
      float MB = scan_min32(eB);
      dcB = SB + ((j == j0) ? 0.f : MB);

      if (l31 && j >= jstore) {
        orowA[j] = sqrtf(dcA);
        orowB[j] = sqrtf(dcB);
      }
    }

    float4* dstb = (float4*)lds[(t + 1) & 1];
    dstb[tid] = st0;
    dstb[tid + 256] = st1;
    if (tid < QT - 512) dstb[tid + 512] = st2;
    __syncthreads();
  }
}

extern "C" void kernel_launch(void* const* d_in, const int* in_sizes, int n_in,
                              void* d_out, int out_size, void* d_ws, size_t ws_size,
                              hipStream_t stream) {
  const float* x     = (const float*)d_in[0];
  const float* patts = (const float*)d_in[1];
  const float* w     = (const float*)d_in[2];
  float* out = (float*)d_out;

  float* xT = (float*)d_ws;                  // B*T*XSTR floats = 2.62 MB

  dtw_transpose<<<(B_ * T_ + 255) / 256, 256, 0, stream>>>(x, xT);
  dtw_kernel<<<B_ * (P_ / 16) * 2, 256, 0, stream>>>(xT, patts, w, out);
}

// Round 9
// 260.239 us; speedup vs baseline: 2.4155x; 1.4474x over previous
//
#include <hip/hip_runtime.h>
#include <math.h>

#define B_ 32
#define D_ 16
#define T_ 1024
#define P_ 64
#define L_ 32
#define XSTR 20            // xT row: 16 x + x2 + pad (80 B)
#define TILE 128           // columns per LDS tile
#define NTILE (T_ / TILE)
#define KB 524288.0f       // 2^19 bias: prefmin(e) = KB - prefmax(KB - e); all u >= 0

typedef float v2f __attribute__((ext_vector_type(2)));

// ---- DPP helpers -----------------------------------------------------------
template<int CTRL, int ROW_MASK, bool BC>
__device__ __forceinline__ float dpp_mov(float old_, float src) {
  int o = __builtin_bit_cast(int, old_);
  int s = __builtin_bit_cast(int, src);
  int r = __builtin_amdgcn_update_dpp(o, s, CTRL, ROW_MASK, 0xf, BC);
  return __builtin_bit_cast(float, r);
}

// Inclusive prefix-sum over each 32-lane half (0-fill -> fused v_add_f32_dpp).
__device__ __forceinline__ float scan_sum32(float v) {
  v += dpp_mov<0x111, 0xf, true>(0.f, v);   // row_shr:1
  v += dpp_mov<0x112, 0xf, true>(0.f, v);   // row_shr:2
  v += dpp_mov<0x114, 0xf, true>(0.f, v);   // row_shr:4
  v += dpp_mov<0x118, 0xf, true>(0.f, v);   // row_shr:8
  v += dpp_mov<0x142, 0xa, false>(0.f, v);  // row_bcast15 -> rows 1,3
  return v;
}

// Inclusive prefix-MAX over each 32-lane half, inputs >= 0 so 0-fill is the
// identity -> every step is ONE fused v_max_f32_dpp (no tied-old copy chain,
// the suspected 3-instr/3-hop cost of the old min-scan).
__device__ __forceinline__ float scan_max32(float v) {
  v = fmaxf(v, dpp_mov<0x111, 0xf, true>(0.f, v));   // row_shr:1
  v = fmaxf(v, dpp_mov<0x112, 0xf, true>(0.f, v));   // row_shr:2
  v = fmaxf(v, dpp_mov<0x114, 0xf, true>(0.f, v));   // row_shr:4
  v = fmaxf(v, dpp_mov<0x118, 0xf, true>(0.f, v));   // row_shr:8
  v = fmaxf(v, dpp_mov<0x142, 0xa, false>(0.f, v));  // row_bcast15 -> rows 1,3
  return v;
}

// ---- transpose: x[b][d][t] -> xT[b][t][XSTR] (x[0..15], x2 at [16]) --------
__global__ void dtw_transpose(const float* __restrict__ x,
                              float* __restrict__ xT) {
  int gid = blockIdx.x * blockDim.x + threadIdx.x;   // 0 .. B*T-1
  if (gid >= B_ * T_) return;
  int b = gid >> 10;
  int j = gid & (T_ - 1);
  float v[D_];
  float s = 0.f;
#pragma unroll
  for (int d = 0; d < D_; ++d) {
    v[d] = x[((size_t)(b * D_ + d)) * T_ + j];
    s = fmaf(v[d], v[d], s);
  }
  float* row = xT + (size_t)gid * XSTR;
  float4* dst = (float4*)row;
#pragma unroll
  for (int q = 0; q < 4; ++q)
    dst[q] = make_float4(v[4*q], v[4*q+1], v[4*q+2], v[4*q+3]);
  row[16] = s;
}

// ---- main DTW kernel -------------------------------------------------------
// Block = (b, 8 patterns), 256 threads; 32 lanes = pattern axis L. Single
// exact stream per group (R4 structure). Column recurrence via two scans:
//   S = prefsum(c);  e = w*min(D,shift(D)) + c - S;  Dnew = S + prefmin(e)
// with prefmin computed as KB - prefmax(KB - e) so the ladder uses 0-fill
// DPP (single-instruction steps). KB=2^19 >> |e| (bounded by ~1e5); the bias
// costs <= 2^-5 ulp/col on D (steady-state error ~3 on D, ~0.06 on output).
__global__ __launch_bounds__(256) void dtw_kernel(
    const float* __restrict__ xT,     // [B][T][XSTR]
    const float* __restrict__ patts,  // [P][D][L]
    const float* __restrict__ wp,
    float* __restrict__ out)          // [B][P][T]
{
  __shared__ float lds[2][TILE * XSTR];   // 2 x 10240 B

  const int tid = threadIdx.x;
  const int li  = tid & 31;
  const int grp = tid >> 5;
  const int b   = blockIdx.x >> 3;
  const int p   = ((blockIdx.x & 7) << 3) + grp;
  const float w = wp[0];
  const bool l0 = (li == 0), l31 = (li == 31);

  // pattern fragment packed for v_pk_fma_f32
  v2f pd2[8];
  float p2 = 0.f;
#pragma unroll
  for (int d = 0; d < D_; ++d) {
    float t = patts[((size_t)p * D_ + d) * L_ + li];
    ((float*)pd2)[d] = t;
    p2 = fmaf(t, t, p2);
  }

  const float4* xg = (const float4*)(xT + (size_t)b * T_ * XSTR);
  float* orow = out + ((size_t)(b * P_ + p)) * T_;

  const int QT = TILE * XSTR / 4;   // 640 float4 per tile

  // ---- stage tile 0 ----
  float4 st0, st1, st2;
  st0 = xg[tid];
  st1 = xg[tid + 256];
  if (tid < QT - 512) st2 = xg[tid + 512];
  ((float4*)lds[0])[tid] = st0;
  ((float4*)lds[0])[tid + 256] = st1;
  if (tid < QT - 512) ((float4*)lds[0])[tid + 512] = st2;
  __syncthreads();

  float dcur = 0.f;   // j==0 handled by uniform select below

  for (int t = 0; t < NTILE; ++t) {
    const int tn = (t + 1 < NTILE) ? t + 1 : t;
    const float4* src = xg + (size_t)tn * QT;
    st0 = src[tid];
    st1 = src[tid + 256];
    if (tid < QT - 512) st2 = src[tid + 512];

    const float* buf = lds[t & 1];
    const int jbase = t * TILE;

#pragma unroll 4
    for (int k = 0; k < TILE; ++k) {
      const int j = jbase + k;
      const float* cp = buf + k * XSTR;
      float4 r0 = *(const float4*)(cp);
      float4 r1 = *(const float4*)(cp + 4);
      float4 r2 = *(const float4*)(cp + 8);
      float4 r3 = *(const float4*)(cp + 12);
      float rs = cp[16];

      v2f q0 = {0.f, 0.f}, q1 = {0.f, 0.f};
      q0 = __builtin_elementwise_fma(*(const v2f*)&r0.x, pd2[0], q0);
      q1 = __builtin_elementwise_fma(*(const v2f*)&r0.z, pd2[1], q1);
      q0 = __builtin_elementwise_fma(*(const v2f*)&r1.x, pd2[2], q0);
      q1 = __builtin_elementwise_fma(*(const v2f*)&r1.z, pd2[3], q1);
      q0 = __builtin_elementwise_fma(*(const v2f*)&r2.x, pd2[4], q0);
      q1 = __builtin_elementwise_fma(*(const v2f*)&r2.z, pd2[5], q1);
      q0 = __builtin_elementwise_fma(*(const v2f*)&r3.x, pd2[6], q0);
      q1 = __builtin_elementwise_fma(*(const v2f*)&r3.z, pd2[7], q1);
      v2f qs = q0 + q1;
      float c = fmaf(-2.f, qs.x + qs.y, rs + p2);

      float S = scan_sum32(c);
      float q = (S - c) + KB;                        // off critical path

      // critical chain: dcur -> pu -> mn -> u -> 5x max-dpp -> dcur
      float pu = dpp_mov<0x138, 0xf, true>(0.f, dcur);   // wave_shr:1, 0-fill
      pu = l0 ? dcur : pu;                               // lane0/32 fix
      float mn = fminf(dcur, pu);
      float u  = fmaf(-w, mn, q);                        // u = KB - e >= 0
      float Mx = scan_max32(u);
      float val = (S + KB) - Mx;                         // S + prefmin(e)
      dcur = (j == 0) ? S : val;                         // col 0 = pure cumsum

      if (l31) orow[j] = __builtin_amdgcn_sqrtf(dcur);
    }

    float4* dstb = (float4*)lds[(t + 1) & 1];
    dstb[tid] = st0;
    dstb[tid + 256] = st1;
    if (tid < QT - 512) dstb[tid + 512] = st2;
    __syncthreads();
  }
}

extern "C" void kernel_launch(void* const* d_in, const int* in_sizes, int n_in,
                              void* d_out, int out_size, void* d_ws, size_t ws_size,
                              hipStream_t stream) {
  const float* x     = (const float*)d_in[0];
  const float* patts = (const float*)d_in[1];
  const float* w     = (const float*)d_in[2];
  float* out = (float*)d_out;

  float* xT = (float*)d_ws;                  // B*T*XSTR floats = 2.62 MB

  dtw_transpose<<<(B_ * T_ + 255) / 256, 256, 0, stream>>>(x, xT);
  dtw_kernel<<<B_ * (P_ / 8), 256, 0, stream>>>(xT, patts, w, out);
}

// Round 10
// 185.059 us; speedup vs baseline: 3.3968x; 1.4062x over previous
//
#include <hip/hip_runtime.h>
#include <math.h>

#define B_ 32
#define D_ 16
#define T_ 1024
#define P_ 64
#define L_ 32
#define KB 524288.0f       // 2^19 bias: prefmin(e) = KB - prefmax(KB - e)

typedef short short8 __attribute__((ext_vector_type(8)));
typedef float f32x4 __attribute__((ext_vector_type(4)));
typedef unsigned short ushort_t;

// ---- DPP helpers -----------------------------------------------------------
template<int CTRL, int ROW_MASK, bool BC>
__device__ __forceinline__ float dpp_mov(float old_, float src) {
  int o = __builtin_bit_cast(int, old_);
  int s = __builtin_bit_cast(int, src);
  int r = __builtin_amdgcn_update_dpp(o, s, CTRL, ROW_MASK, 0xf, BC);
  return __builtin_bit_cast(float, r);
}

// Inclusive prefix-sum over each 32-lane half (0-fill -> fused v_add_f32_dpp).
__device__ __forceinline__ float scan_sum32(float v) {
  v += dpp_mov<0x111, 0xf, true>(0.f, v);   // row_shr:1
  v += dpp_mov<0x112, 0xf, true>(0.f, v);   // row_shr:2
  v += dpp_mov<0x114, 0xf, true>(0.f, v);   // row_shr:4
  v += dpp_mov<0x118, 0xf, true>(0.f, v);   // row_shr:8
  v += dpp_mov<0x142, 0xa, false>(0.f, v);  // row_bcast15 -> rows 1,3
  return v;
}

// Inclusive prefix-MAX over each 32-lane half, inputs >= 0 (0-fill identity).
__device__ __forceinline__ float scan_max32(float v) {
  v = fmaxf(v, dpp_mov<0x111, 0xf, true>(0.f, v));
  v = fmaxf(v, dpp_mov<0x112, 0xf, true>(0.f, v));
  v = fmaxf(v, dpp_mov<0x114, 0xf, true>(0.f, v));
  v = fmaxf(v, dpp_mov<0x118, 0xf, true>(0.f, v));
  v = fmaxf(v, dpp_mov<0x142, 0xa, false>(0.f, v));
  return v;
}

__device__ __forceinline__ ushort_t f2bf(float f) {   // fp32 -> bf16 RNE
  unsigned u = __builtin_bit_cast(unsigned, f);
  return (ushort_t)((u + 0x7FFFu + ((u >> 16) & 1u)) >> 16);
}
__device__ __forceinline__ float bf2f(ushort_t h) {
  unsigned u = ((unsigned)h) << 16;
  return __builtin_bit_cast(float, u);
}

// ---- prep: x[b][d][t] -> A-operand rows xA[b][t][32 bf16] ------------------
// channels: [0..15]=x, [16]=1, [17]=1, [18]=x2hi, [19]=x2lo, [20..31]=0
__global__ void prep_x(const float* __restrict__ x, ushort_t* __restrict__ xA) {
  int gid = blockIdx.x * blockDim.x + threadIdx.x;
  if (gid >= B_ * T_) return;
  int b = gid >> 10, t = gid & 1023;
  float x2 = 0.f;
  ushort_t o[32];
#pragma unroll
  for (int d = 0; d < 16; ++d) {
    float v = x[((b * 16 + d) << 10) + t];   // coalesced over t
    x2 = fmaf(v, v, x2);
    o[d] = f2bf(v);
  }
  o[16] = 0x3F80; o[17] = 0x3F80;            // bf16(1.0)
  ushort_t hi = f2bf(x2);
  o[18] = hi;
  o[19] = f2bf(x2 - bf2f(hi));               // hi/lo split: ~2^-16 rel err
#pragma unroll
  for (int d = 20; d < 32; ++d) o[d] = 0;
  uint4* dst = (uint4*)(xA + (size_t)gid * 32);
#pragma unroll
  for (int q = 0; q < 4; ++q) {
    const ushort_t* s = o + q * 8;
    uint4 u;
    u.x = (unsigned)s[0] | ((unsigned)s[1] << 16);
    u.y = (unsigned)s[2] | ((unsigned)s[3] << 16);
    u.z = (unsigned)s[4] | ((unsigned)s[5] << 16);
    u.w = (unsigned)s[6] | ((unsigned)s[7] << 16);
    dst[q] = u;
  }
}

// ---- prep: B-operand fragments pB[p][iblk][lane][8 bf16] -------------------
// B[k][n]: n=lane&15, k=(lane>>4)*8+e. k<16: -2*patt; k=16/17: p2hi/p2lo;
// k=18/19: 1; k>=20: 0.
__global__ void prep_patt(const float* __restrict__ patts,
                          ushort_t* __restrict__ pB) {
  int gid = blockIdx.x * blockDim.x + threadIdx.x;
  if (gid >= P_ * 2 * 64) return;
  int lane = gid & 63, iblk = (gid >> 6) & 1, p = gid >> 7;
  int n = lane & 15, q = lane >> 4;
  int i = iblk * 16 + n;
  ushort_t o[8];
  if (q < 2) {
#pragma unroll
    for (int e = 0; e < 8; ++e) {
      int k = q * 8 + e;
      o[e] = f2bf(-2.f * patts[((p * 16 + k) << 5) + i]);
    }
  } else if (q == 2) {
    float p2 = 0.f;
#pragma unroll
    for (int k = 0; k < 16; ++k) {
      float t = patts[((p * 16 + k) << 5) + i];
      p2 = fmaf(t, t, p2);
    }
    ushort_t hi = f2bf(p2);
    o[0] = hi; o[1] = f2bf(p2 - bf2f(hi));
    o[2] = 0x3F80; o[3] = 0x3F80;
    o[4] = o[5] = o[6] = o[7] = 0;
  } else {
#pragma unroll
    for (int e = 0; e < 8; ++e) o[e] = 0;
  }
  uint4 u;
  u.x = (unsigned)o[0] | ((unsigned)o[1] << 16);
  u.y = (unsigned)o[2] | ((unsigned)o[3] << 16);
  u.z = (unsigned)o[4] | ((unsigned)o[5] << 16);
  u.w = (unsigned)o[6] | ((unsigned)o[7] << 16);
  ((uint4*)pB)[gid] = u;
}

// ---- main kernel -----------------------------------------------------------
// 256 blocks x 256 thr. Wave = 2 patterns (lanes 0-31 / 32-63). Per 16-col
// tile: 1 global A-frag load (dist-2 prefetch) + 4 MFMAs produce the COMPLETE
// cost tile (x2/p2 folded via aux channels) -> 4 ds_write_b128 into per-wave
// LDS scratch [i][j] (stride 20, 16B-aligned rows). DP consumes 1 b128 per
// 4 columns. No cross-wave sharing -> no barriers. B-frags are MFMA operands
// -> structurally register-resident (defeats the R2-R6 demotion).
__global__ __launch_bounds__(256, 1) void dtw_kernel(
    const ushort_t* __restrict__ xA,    // [B][T][32 bf16]
    const ushort_t* __restrict__ pBg,   // [P][2][64][8 bf16]
    const float* __restrict__ wp,
    float* __restrict__ out)            // [B][P][T]
{
  __shared__ float lds[4 * 2560];   // 4 waves * 2 buf * 2 pat * (32*20) fl

  const int tid = threadIdx.x;
  const int l   = tid & 63;
  const int wid = tid >> 6;
  const int li  = l & 31;
  const int g   = l >> 5;
  const int q4  = l >> 4;
  const int b   = blockIdx.x >> 3;
  const int pbase = (blockIdx.x & 7) << 3;
  const int pA  = pbase + (wid << 1);
  const float w = wp[0];
  const bool l0c = (li == 0), l31 = (li == 31);

  // B fragments (loop-invariant MFMA operands)
  const short8* pBs = (const short8*)pBg;
  short8 B00 = pBs[((pA    ) * 2 + 0) * 64 + l];
  short8 B01 = pBs[((pA    ) * 2 + 1) * 64 + l];
  short8 B10 = pBs[((pA + 1) * 2 + 0) * 64 + l];
  short8 B11 = pBs[((pA + 1) * 2 + 1) * 64 + l];

  const short8* xAs = (const short8*)xA + ((size_t)b << 12);  // 4 frags/col

  auto loadA = [&](int t, short8& a) {
    a = xAs[(((t << 4) + (l & 15)) << 2) + q4];
  };

  float* ldsW = lds + wid * 2560 + (l & 15) * 20 + q4 * 4;   // +buf*1280+pat*640+iblk*320
  const float* ldsR = lds + wid * 2560 + g * 640 + li * 20;  // +buf*1280 + j

  auto fill = [&](int bufsel, short8 a) {
    f32x4 z = {0.f, 0.f, 0.f, 0.f};
    float* wb = ldsW + bufsel * 1280;
    f32x4 d0 = __builtin_amdgcn_mfma_f32_16x16x32_bf16(a, B00, z, 0, 0, 0);
    f32x4 d1 = __builtin_amdgcn_mfma_f32_16x16x32_bf16(a, B01, z, 0, 0, 0);
    f32x4 d2 = __builtin_amdgcn_mfma_f32_16x16x32_bf16(a, B10, z, 0, 0, 0);
    f32x4 d3 = __builtin_amdgcn_mfma_f32_16x16x32_bf16(a, B11, z, 0, 0, 0);
    *(f32x4*)(wb + 0)   = d0;      // pat0, i 0..15
    *(f32x4*)(wb + 320) = d1;      // pat0, i 16..31
    *(f32x4*)(wb + 640) = d2;      // pat1, i 0..15
    *(f32x4*)(wb + 960) = d3;      // pat1, i 16..31
  };

  float* orow = out + (((size_t)(b * P_ + pA + g)) << 10);
  float dcur = 0.f;

  auto DP = [&](int t, int bufsel) {
    const float* rb = ldsR + bufsel * 1280;
    const int jg0 = t << 4;
#pragma unroll
    for (int k4 = 0; k4 < 4; ++k4) {
      f32x4 cq = *(const f32x4*)(rb + k4 * 4);
#pragma unroll
      for (int e = 0; e < 4; ++e) {
        const int jg = jg0 + k4 * 4 + e;
        float c = cq[e];
        float S = scan_sum32(c);
        float qv = (S - c) + KB;                           // off critical path
        float pu = dpp_mov<0x138, 0xf, true>(0.f, dcur);   // wave_shr:1
        pu = l0c ? dcur : pu;
        float mn = fminf(dcur, pu);
        float u  = fmaf(-w, mn, qv);                       // KB - e >= 0
        float Mx = scan_max32(u);
        float val = (S + KB) - Mx;
        dcur = (jg == 0) ? S : val;                        // col 0 = cumsum
        if (l31) orow[jg] = __builtin_amdgcn_sqrtf(dcur);
      }
    }
  };

  short8 Ae, Ao;
  loadA(0, Ae); loadA(1, Ao);
  fill(0, Ae);
  for (int t = 0; t < 64; t += 2) {
    fill(1, Ao);
    if (t < 62) loadA(t + 2, Ae);
    DP(t, 0);
    if (t < 62) { fill(0, Ae); loadA(t + 3, Ao); }
    DP(t + 1, 1);
  }
}

extern "C" void kernel_launch(void* const* d_in, const int* in_sizes, int n_in,
                              void* d_out, int out_size, void* d_ws, size_t ws_size,
                              hipStream_t stream) {
  const float* x     = (const float*)d_in[0];
  const float* patts = (const float*)d_in[1];
  const float* w     = (const float*)d_in[2];
  float* out = (float*)d_out;

  ushort_t* xA = (ushort_t*)d_ws;                        // 2 MiB
  ushort_t* pB = (ushort_t*)((char*)d_ws + (size_t)B_ * T_ * 32 * 2);  // 128 KiB

  prep_x<<<(B_ * T_ + 255) / 256, 256, 0, stream>>>(x, xA);
  prep_patt<<<(P_ * 2 * 64 + 255) / 256, 256, 0, stream>>>(patts, pB);
  dtw_kernel<<<B_ * (P_ / 8), 256, 0, stream>>>(xA, pB, w, out);
}

// Round 11
// 179.973 us; speedup vs baseline: 3.4928x; 1.0283x over previous
//
#include <hip/hip_runtime.h>
#include <math.h>

#define B_ 32
#define D_ 16
#define T_ 1024
#define P_ 64
#define L_ 32
#define KB 524288.0f       // 2^19 bias: prefmin(e) = KB - prefmax(KB - e)

typedef short short8 __attribute__((ext_vector_type(8)));
typedef float f32x4 __attribute__((ext_vector_type(4)));
typedef unsigned short ushort_t;

// ---- DPP helpers -----------------------------------------------------------
template<int CTRL, int ROW_MASK, bool BC>
__device__ __forceinline__ float dpp_mov(float old_, float src) {
  int o = __builtin_bit_cast(int, old_);
  int s = __builtin_bit_cast(int, src);
  int r = __builtin_amdgcn_update_dpp(o, s, CTRL, ROW_MASK, 0xf, BC);
  return __builtin_bit_cast(float, r);
}

// Inclusive prefix-sum over each 32-lane half (0-fill -> fused v_add_f32_dpp).
__device__ __forceinline__ float scan_sum32(float v) {
  v += dpp_mov<0x111, 0xf, true>(0.f, v);   // row_shr:1
  v += dpp_mov<0x112, 0xf, true>(0.f, v);   // row_shr:2
  v += dpp_mov<0x114, 0xf, true>(0.f, v);   // row_shr:4
  v += dpp_mov<0x118, 0xf, true>(0.f, v);   // row_shr:8
  v += dpp_mov<0x142, 0xa, false>(0.f, v);  // row_bcast15 -> rows 1,3
  return v;
}

// Inclusive prefix-MAX over each 32-lane half, inputs >= 0 (0-fill identity).
__device__ __forceinline__ float scan_max32(float v) {
  v = fmaxf(v, dpp_mov<0x111, 0xf, true>(0.f, v));
  v = fmaxf(v, dpp_mov<0x112, 0xf, true>(0.f, v));
  v = fmaxf(v, dpp_mov<0x114, 0xf, true>(0.f, v));
  v = fmaxf(v, dpp_mov<0x118, 0xf, true>(0.f, v));
  v = fmaxf(v, dpp_mov<0x142, 0xa, false>(0.f, v));
  return v;
}

__device__ __forceinline__ ushort_t f2bf(float f) {   // fp32 -> bf16 RNE
  unsigned u = __builtin_bit_cast(unsigned, f);
  return (ushort_t)((u + 0x7FFFu + ((u >> 16) & 1u)) >> 16);
}
__device__ __forceinline__ float bf2f(ushort_t h) {
  unsigned u = ((unsigned)h) << 16;
  return __builtin_bit_cast(float, u);
}

// ---- fused prep: xA A-operand rows + pB B-operand fragments ----------------
// xA[b][t][32 bf16]: [0..15]=x, [16..17]=1, [18..19]=x2hi/lo, [20..31]=0
// pB[p][iblk][lane][8 bf16]: k<16: -2*patt; k=16/17: p2hi/lo; k=18/19: 1.
__global__ void prep_all(const float* __restrict__ x,
                         const float* __restrict__ patts,
                         ushort_t* __restrict__ xA,
                         ushort_t* __restrict__ pB) {
  int gid = blockIdx.x * blockDim.x + threadIdx.x;
  if (gid < B_ * T_) {
    int b = gid >> 10, t = gid & 1023;
    float x2 = 0.f;
    ushort_t o[32];
#pragma unroll
    for (int d = 0; d < 16; ++d) {
      float v = x[((b * 16 + d) << 10) + t];   // coalesced over t
      x2 = fmaf(v, v, x2);
      o[d] = f2bf(v);
    }
    o[16] = 0x3F80; o[17] = 0x3F80;            // bf16(1.0)
    ushort_t hi = f2bf(x2);
    o[18] = hi;
    o[19] = f2bf(x2 - bf2f(hi));               // hi/lo split
#pragma unroll
    for (int d = 20; d < 32; ++d) o[d] = 0;
    uint4* dst = (uint4*)(xA + (size_t)gid * 32);
#pragma unroll
    for (int q = 0; q < 4; ++q) {
      const ushort_t* s = o + q * 8;
      uint4 u;
      u.x = (unsigned)s[0] | ((unsigned)s[1] << 16);
      u.y = (unsigned)s[2] | ((unsigned)s[3] << 16);
      u.z = (unsigned)s[4] | ((unsigned)s[5] << 16);
      u.w = (unsigned)s[6] | ((unsigned)s[7] << 16);
      dst[q] = u;
    }
  } else {
    int g2 = gid - B_ * T_;
    if (g2 >= P_ * 2 * 64) return;
    int lane = g2 & 63, iblk = (g2 >> 6) & 1, p = g2 >> 7;
    int n = lane & 15, q = lane >> 4;
    int i = iblk * 16 + n;
    ushort_t o[8];
    if (q < 2) {
#pragma unroll
      for (int e = 0; e < 8; ++e) {
        int k = q * 8 + e;
        o[e] = f2bf(-2.f * patts[((p * 16 + k) << 5) + i]);
      }
    } else if (q == 2) {
      float p2 = 0.f;
#pragma unroll
      for (int k = 0; k < 16; ++k) {
        float t = patts[((p * 16 + k) << 5) + i];
        p2 = fmaf(t, t, p2);
      }
      ushort_t hi = f2bf(p2);
      o[0] = hi; o[1] = f2bf(p2 - bf2f(hi));
      o[2] = 0x3F80; o[3] = 0x3F80;
      o[4] = o[5] = o[6] = o[7] = 0;
    } else {
#pragma unroll
      for (int e = 0; e < 8; ++e) o[e] = 0;
    }
    uint4 u;
    u.x = (unsigned)o[0] | ((unsigned)o[1] << 16);
    u.y = (unsigned)o[2] | ((unsigned)o[3] << 16);
    u.z = (unsigned)o[4] | ((unsigned)o[5] << 16);
    u.w = (unsigned)o[6] | ((unsigned)o[7] << 16);
    ((uint4*)pB)[g2] = u;
  }
}

// ---- main kernel -----------------------------------------------------------
// 768 blocks x 256 thr = 3 blocks/CU (3 waves/SIMD: stall overlap — R5
// measured 1.86x hiding at this wave count). Each block: one (b, 8-pattern,
// chunk) triple. Chunks (tile-aligned, balanced 37/37/38 tiles, W=384 cols
// warm-up, w^384=2.4e-4): c0 computes tiles 0-36 stores j<592; c1 tiles
// 13-49 stores 592-799; c2 tiles 26-63 stores 800-1023. Warm-up inits with
// a cumsum column (R5-verified semantics). Per 16-col tile: 1 A-frag global
// load + 4 MFMAs -> complete cost tile in per-wave LDS; DP consumes 1
// ds_read_b128 per 4 columns with distance-1 register prefetch.
__global__ __launch_bounds__(256, 3) void dtw_kernel(
    const ushort_t* __restrict__ xA,    // [B][T][32 bf16]
    const ushort_t* __restrict__ pBg,   // [P][2][64][8 bf16]
    const float* __restrict__ wp,
    float* __restrict__ out)            // [B][P][T]
{
  __shared__ float lds[4 * 2560];   // 4 waves * 2 buf * 2 pat * (32*20) fl

  const int tid = threadIdx.x;
  const int l   = tid & 63;
  const int wid = tid >> 6;
  const int li  = l & 31;
  const int g   = l >> 5;
  const int q4  = l >> 4;
  const unsigned bx = blockIdx.x;
  const int ch   = bx % 3u;
  const int rest = bx / 3u;
  const int b     = rest >> 3;
  const int pbase = (rest & 7) << 3;
  const int pA  = pbase + (wid << 1);
  const float w = wp[0];
  const bool l0c = (li == 0), l31 = (li == 31);

  const int t0     = (ch == 0) ? 0 : (ch == 1 ? 13 : 26);
  const int NT     = (ch == 2) ? 38 : 37;
  const int jstore = (ch == 0) ? 0 : (ch == 1 ? 592 : 800);
  const int jfirst = t0 << 4;

  // B fragments (loop-invariant MFMA operands -> register-resident)
  const short8* pBs = (const short8*)pBg;
  short8 B00 = pBs[((pA    ) * 2 + 0) * 64 + l];
  short8 B01 = pBs[((pA    ) * 2 + 1) * 64 + l];
  short8 B10 = pBs[((pA + 1) * 2 + 0) * 64 + l];
  short8 B11 = pBs[((pA + 1) * 2 + 1) * 64 + l];

  const short8* xAs = (const short8*)xA + ((size_t)b << 12);  // 4 frags/col

  short8 Aa;
  auto loadA = [&](int t) {   // t = local tile index
    Aa = xAs[((((t0 + t) << 4) + (l & 15)) << 2) + q4];
  };

  float* ldsW = lds + wid * 2560 + (l & 15) * 20 + q4 * 4;
  const float* ldsR = lds + wid * 2560 + g * 640 + li * 20;

  auto fill = [&](int bufsel) {
    f32x4 z = {0.f, 0.f, 0.f, 0.f};
    float* wb = ldsW + bufsel * 1280;
    f32x4 d0 = __builtin_amdgcn_mfma_f32_16x16x32_bf16(Aa, B00, z, 0, 0, 0);
    f32x4 d1 = __builtin_amdgcn_mfma_f32_16x16x32_bf16(Aa, B01, z, 0, 0, 0);
    f32x4 d2 = __builtin_amdgcn_mfma_f32_16x16x32_bf16(Aa, B10, z, 0, 0, 0);
    f32x4 d3 = __builtin_amdgcn_mfma_f32_16x16x32_bf16(Aa, B11, z, 0, 0, 0);
    *(f32x4*)(wb + 0)   = d0;      // pat0, i 0..15   ([i][j] stride 20)
    *(f32x4*)(wb + 320) = d1;      // pat0, i 16..31
    *(f32x4*)(wb + 640) = d2;      // pat1, i 0..15
    *(f32x4*)(wb + 960) = d3;      // pat1, i 16..31
  };

  float* orow = out + (((size_t)(b * P_ + pA + g)) << 10);
  float dcur = 0.f;

  auto DP = [&](int t, int bufsel) {
    const float* rb = ldsR + bufsel * 1280;
    const int jg0 = (t0 + t) << 4;
    f32x4 cq = *(const f32x4*)(rb);
#pragma unroll
    for (int k4 = 0; k4 < 4; ++k4) {
      f32x4 cqn = cq;
      if (k4 < 3) cqn = *(const f32x4*)(rb + (k4 + 1) * 4);  // dist-1 prefetch
#pragma unroll
      for (int e = 0; e < 4; ++e) {
        const int jg = jg0 + k4 * 4 + e;
        float c = cq[e];
        float S = scan_sum32(c);
        float qv = (S - c) + KB;                           // off critical path
        float pu = dpp_mov<0x138, 0xf, true>(0.f, dcur);   // wave_shr:1
        pu = l0c ? dcur : pu;
        float mn = fminf(dcur, pu);
        float u  = fmaf(-w, mn, qv);                       // KB - e >= 0
        float Mx = scan_max32(u);
        float val = (S + KB) - Mx;
        dcur = (jg == jfirst) ? S : val;                   // init col = cumsum
        if (l31 && jg >= jstore) orow[jg] = __builtin_amdgcn_sqrtf(dcur);
      }
      cq = cqn;
    }
  };

  loadA(0);
  fill(0);
  loadA(1);
  for (int t = 0; t < NT; ++t) {
    if (t + 1 < NT) fill((t & 1) ^ 1);   // consumes Aa = frag(t+1)
    if (t + 2 < NT) loadA(t + 2);
    DP(t, t & 1);
  }
}

extern "C" void kernel_launch(void* const* d_in, const int* in_sizes, int n_in,
                              void* d_out, int out_size, void* d_ws, size_t ws_size,
                              hipStream_t stream) {
  const float* x     = (const float*)d_in[0];
  const float* patts = (const float*)d_in[1];
  const float* w     = (const float*)d_in[2];
  float* out = (float*)d_out;

  ushort_t* xA = (ushort_t*)d_ws;                                       // 2 MiB
  ushort_t* pB = (ushort_t*)((char*)d_ws + (size_t)B_ * T_ * 32 * 2);   // 128 KiB

  prep_all<<<(B_ * T_ + P_ * 2 * 64 + 255) / 256, 256, 0, stream>>>(x, patts, xA, pB);
  dtw_kernel<<<B_ * (P_ / 8) * 3, 256, 0, stream>>>(xA, pB, w, out);
}

// Round 12
// 153.848 us; speedup vs baseline: 4.0859x; 1.1698x over previous
//
#include <hip/hip_runtime.h>
#include <math.h>

#define B_ 32
#define D_ 16
#define T_ 1024
#define P_ 64
#define L_ 32
#define KB 524288.0f       // 2^19 bias: prefmin(e) = KB - prefmax(KB - e)

typedef short short8 __attribute__((ext_vector_type(8)));
typedef float f32x4 __attribute__((ext_vector_type(4)));
typedef unsigned short ushort_t;

// ---- DPP helpers -----------------------------------------------------------
template<int CTRL, int ROW_MASK, bool BC>
__device__ __forceinline__ float dpp_mov(float old_, float src) {
  int o = __builtin_bit_cast(int, old_);
  int s = __builtin_bit_cast(int, src);
  int r = __builtin_amdgcn_update_dpp(o, s, CTRL, ROW_MASK, 0xf, BC);
  return __builtin_bit_cast(float, r);
}

// Inclusive prefix-sum over each 32-lane half (0-fill -> fused v_add_f32_dpp).
__device__ __forceinline__ float scan_sum32(float v) {
  v += dpp_mov<0x111, 0xf, true>(0.f, v);   // row_shr:1
  v += dpp_mov<0x112, 0xf, true>(0.f, v);   // row_shr:2
  v += dpp_mov<0x114, 0xf, true>(0.f, v);   // row_shr:4
  v += dpp_mov<0x118, 0xf, true>(0.f, v);   // row_shr:8
  v += dpp_mov<0x142, 0xa, false>(0.f, v);  // row_bcast15 -> rows 1,3
  return v;
}

// Inclusive prefix-MAX over each 32-lane half, inputs >= 0 (0-fill identity).
__device__ __forceinline__ float scan_max32(float v) {
  v = fmaxf(v, dpp_mov<0x111, 0xf, true>(0.f, v));
  v = fmaxf(v, dpp_mov<0x112, 0xf, true>(0.f, v));
  v = fmaxf(v, dpp_mov<0x114, 0xf, true>(0.f, v));
  v = fmaxf(v, dpp_mov<0x118, 0xf, true>(0.f, v));
  v = fmaxf(v, dpp_mov<0x142, 0xa, false>(0.f, v));
  return v;
}

__device__ __forceinline__ ushort_t f2bf(float f) {   // fp32 -> bf16 RNE
  unsigned u = __builtin_bit_cast(unsigned, f);
  return (ushort_t)((u + 0x7FFFu + ((u >> 16) & 1u)) >> 16);
}
__device__ __forceinline__ float bf2f(ushort_t h) {
  unsigned u = ((unsigned)h) << 16;
  return __builtin_bit_cast(float, u);
}

// ---- fused prep: xA A-operand rows + pB B-operand fragments ----------------
__global__ void prep_all(const float* __restrict__ x,
                         const float* __restrict__ patts,
                         ushort_t* __restrict__ xA,
                         ushort_t* __restrict__ pB) {
  int gid = blockIdx.x * blockDim.x + threadIdx.x;
  if (gid < B_ * T_) {
    int b = gid >> 10, t = gid & 1023;
    float x2 = 0.f;
    ushort_t o[32];
#pragma unroll
    for (int d = 0; d < 16; ++d) {
      float v = x[((b * 16 + d) << 10) + t];   // coalesced over t
      x2 = fmaf(v, v, x2);
      o[d] = f2bf(v);
    }
    o[16] = 0x3F80; o[17] = 0x3F80;            // bf16(1.0)
    ushort_t hi = f2bf(x2);
    o[18] = hi;
    o[19] = f2bf(x2 - bf2f(hi));               // hi/lo split
#pragma unroll
    for (int d = 20; d < 32; ++d) o[d] = 0;
    uint4* dst = (uint4*)(xA + (size_t)gid * 32);
#pragma unroll
    for (int q = 0; q < 4; ++q) {
      const ushort_t* s = o + q * 8;
      uint4 u;
      u.x = (unsigned)s[0] | ((unsigned)s[1] << 16);
      u.y = (unsigned)s[2] | ((unsigned)s[3] << 16);
      u.z = (unsigned)s[4] | ((unsigned)s[5] << 16);
      u.w = (unsigned)s[6] | ((unsigned)s[7] << 16);
      dst[q] = u;
    }
  } else {
    int g2 = gid - B_ * T_;
    if (g2 >= P_ * 2 * 64) return;
    int lane = g2 & 63, iblk = (g2 >> 6) & 1, p = g2 >> 7;
    int n = lane & 15, q = lane >> 4;
    int i = iblk * 16 + n;
    ushort_t o[8];
    if (q < 2) {
#pragma unroll
      for (int e = 0; e < 8; ++e) {
        int k = q * 8 + e;
        o[e] = f2bf(-2.f * patts[((p * 16 + k) << 5) + i]);
      }
    } else if (q == 2) {
      float p2 = 0.f;
#pragma unroll
      for (int k = 0; k < 16; ++k) {
        float t = patts[((p * 16 + k) << 5) + i];
        p2 = fmaf(t, t, p2);
      }
      ushort_t hi = f2bf(p2);
      o[0] = hi; o[1] = f2bf(p2 - bf2f(hi));
      o[2] = 0x3F80; o[3] = 0x3F80;
      o[4] = o[5] = o[6] = o[7] = 0;
    } else {
#pragma unroll
      for (int e = 0; e < 8; ++e) o[e] = 0;
    }
    uint4 u;
    u.x = (unsigned)o[0] | ((unsigned)o[1] << 16);
    u.y = (unsigned)o[2] | ((unsigned)o[3] << 16);
    u.z = (unsigned)o[4] | ((unsigned)o[5] << 16);
    u.w = (unsigned)o[6] | ((unsigned)o[7] << 16);
    ((uint4*)pB)[g2] = u;
  }
}

// ---- main kernel -----------------------------------------------------------
// 768 blocks x 256 thr = 3 blocks/CU. Wave = 2 patterns. Per 16-col tile:
// 1 A-frag global load + 4 MFMAs -> complete cost tile in per-wave LDS.
// R11 hit VALUBusy 83% (issue-bound) at ~35 slots/col; this round cuts the
// loop to the ~17-slot core: peeled init, warm tiles (no store path at all),
// store tiles batch 4 sqrt + 1 dwordx4 per 4 cols, tied-DPP only on bcast15.
// Chunks (W=256, w^256=3.9e-3): every block 32 tiles -> work 1.5x (was 1.75).
__global__ __launch_bounds__(256, 3) void dtw_kernel(
    const ushort_t* __restrict__ xA,    // [B][T][32 bf16]
    const ushort_t* __restrict__ pBg,   // [P][2][64][8 bf16]
    const float* __restrict__ wp,
    float* __restrict__ out)            // [B][P][T]
{
  __shared__ float lds[4 * 2560];   // 4 waves * 2 buf * 2 pat * (32*20) fl

  const int tid = threadIdx.x;
  const int l   = tid & 63;
  const int wid = tid >> 6;
  const int li  = l & 31;
  const int g   = l >> 5;
  const int q4  = l >> 4;
  const unsigned bx = blockIdx.x;
  const int ch   = bx % 3u;               // chunk: tiles [16ch, 16ch+32)
  const int rest = bx / 3u;
  const int b     = rest >> 3;
  const int pbase = (rest & 7) << 3;
  const int pA  = pbase + (wid << 1);
  const float w = wp[0];
  const bool l0c = (li == 0), l31 = (li == 31);

  const int t0    = ch << 4;              // 0 / 16 / 32
  const int warmT = ch ? 16 : 0;          // local tiles < warmT: no store

  // B fragments (loop-invariant MFMA operands -> register-resident)
  const short8* pBs = (const short8*)pBg;
  short8 B00 = pBs[((pA    ) * 2 + 0) * 64 + l];
  short8 B01 = pBs[((pA    ) * 2 + 1) * 64 + l];
  short8 B10 = pBs[((pA + 1) * 2 + 0) * 64 + l];
  short8 B11 = pBs[((pA + 1) * 2 + 1) * 64 + l];

  const short8* xAs = (const short8*)xA + ((size_t)b << 12);

  short8 Aa;
  auto loadA = [&](int t) {   // t local; global tile = t0 + t
    Aa = xAs[((((t0 + t) << 4) + (l & 15)) << 2) + q4];
  };

  float* ldsW = lds + wid * 2560 + (l & 15) * 20 + q4 * 4;
  const float* ldsR = lds + wid * 2560 + g * 640 + li * 20;

  auto fill = [&](int bufsel) {
    f32x4 z = {0.f, 0.f, 0.f, 0.f};
    float* wb = ldsW + bufsel * 1280;
    f32x4 d0 = __builtin_amdgcn_mfma_f32_16x16x32_bf16(Aa, B00, z, 0, 0, 0);
    f32x4 d1 = __builtin_amdgcn_mfma_f32_16x16x32_bf16(Aa, B01, z, 0, 0, 0);
    f32x4 d2 = __builtin_amdgcn_mfma_f32_16x16x32_bf16(Aa, B10, z, 0, 0, 0);
    f32x4 d3 = __builtin_amdgcn_mfma_f32_16x16x32_bf16(Aa, B11, z, 0, 0, 0);
    *(f32x4*)(wb + 0)   = d0;      // pat0, i 0..15   ([i][j] stride 20)
    *(f32x4*)(wb + 320) = d1;      // pat0, i 16..31
    *(f32x4*)(wb + 640) = d2;      // pat1, i 0..15
    *(f32x4*)(wb + 960) = d3;      // pat1, i 16..31
  };

  float* orow = out + (((size_t)(b * P_ + pA + g)) << 10) + (t0 << 4);
  float dcur = 0.f;

  // core column update: 17 issue slots, 1 runtime branch nowhere
  auto col = [&](float c) -> float {
    float S  = scan_sum32(c);
    float Sp = S + KB;
    float qv = Sp - c;                                // off critical path
    float pu = dpp_mov<0x138, 0xf, true>(0.f, dcur);  // wave_shr:1, 0-fill
    pu = l0c ? dcur : pu;
    float mn = fminf(dcur, pu);
    float u  = fmaf(-w, mn, qv);                      // KB - e >= 0
    float Mx = scan_max32(u);
    return Sp - Mx;                                   // S + prefmin(e)
  };

  auto DP = [&](int bufsel, bool first, bool store, float* op) {
    const float* rb = ldsR + bufsel * 1280;
    f32x4 q0 = *(const f32x4*)(rb + 0);     // 4 reads up-front: one lgkm
    f32x4 q1 = *(const f32x4*)(rb + 4);     // cluster, staged waits
    f32x4 q2 = *(const f32x4*)(rb + 8);
    f32x4 q3 = *(const f32x4*)(rb + 12);
#pragma unroll
    for (int k4 = 0; k4 < 4; ++k4) {
      f32x4 cq = (k4 == 0) ? q0 : (k4 == 1) ? q1 : (k4 == 2) ? q2 : q3;
      float sv0, sv1, sv2, sv3;
#pragma unroll
      for (int e = 0; e < 4; ++e) {
        float val = col(cq[e]);
        if (first && k4 == 0 && e == 0)                 // uniform, once
          val = scan_sum32(cq[0]);                      // init col = cumsum
        dcur = val;
        if (e == 0) sv0 = val; else if (e == 1) sv1 = val;
        else if (e == 2) sv2 = val; else sv3 = val;
      }
      if (store) {                                      // uniform per tile
        float4 sv;
        sv.x = __builtin_amdgcn_sqrtf(sv0);
        sv.y = __builtin_amdgcn_sqrtf(sv1);
        sv.z = __builtin_amdgcn_sqrtf(sv2);
        sv.w = __builtin_amdgcn_sqrtf(sv3);
        if (l31) *(float4*)(op + k4 * 4) = sv;          // 1 dwordx4 / 4 cols
      }
    }
  };

  loadA(0);
  fill(0);
  loadA(1);
  for (int t = 0; t < 32; ++t) {
    if (t + 1 < 32) fill((t & 1) ^ 1);   // consumes Aa = frag(t+1)
    if (t + 2 < 32) loadA(t + 2);
    DP(t & 1, t == 0, t >= warmT, orow + (t << 4));
  }
}

extern "C" void kernel_launch(void* const* d_in, const int* in_sizes, int n_in,
                              void* d_out, int out_size, void* d_ws, size_t ws_size,
                              hipStream_t stream) {
  const float* x     = (const float*)d_in[0];
  const float* patts = (const float*)d_in[1];
  const float* w     = (const float*)d_in[2];
  float* out = (float*)d_out;

  ushort_t* xA = (ushort_t*)d_ws;                                       // 2 MiB
  ushort_t* pB = (ushort_t*)((char*)d_ws + (size_t)B_ * T_ * 32 * 2);   // 128 KiB

  prep_all<<<(B_ * T_ + P_ * 2 * 64 + 255) / 256, 256, 0, stream>>>(x, patts, xA, pB);
  dtw_kernel<<<B_ * (P_ / 8) * 3, 256, 0, stream>>>(xA, pB, w, out);
}